// Round 5
// baseline (87.311 us; speedup 1.0000x reference)
//
#include <hip/hip_runtime.h>
#include <hip/hip_bf16.h>

typedef __attribute__((ext_vector_type(8))) short bf16x8;
typedef __attribute__((ext_vector_type(4))) float f32x4;

#define KD 2304
#define PL 4228                      // padded plane stride (elems) for xfn
#define OUT_PER_B (256 * 1024)

static __device__ __forceinline__ ushort f2bf(float f) {
  union { float f; unsigned int i; } v; v.f = f;
  unsigned int x = v.i;
  x += 0x7fffu + ((x >> 16) & 1u);   // round-to-nearest-even
  return (ushort)(x >> 16);
}

#define GLDS16(gp, lp)                                                         \
  __builtin_amdgcn_global_load_lds(                                            \
      (const __attribute__((address_space(1))) void*)(gp),                     \
      (__attribute__((address_space(3))) void*)(lp), 16, 0, 0)

// ---------------- Kernel 1: separable 4x4 FIR, pad 2, per (b,c) plane -----------
// f32 [64][64] -> bf16 [65][65] flat (plane stride PL). All LDS traffic b128.
// sxp[64][76]: input row r at cols 4..67 (col = w+4); cols 2,3,68,69 zero halo.
// stp[68][68]: h-filtered row i' at row i'+2, cols 0..64; rows 0,1,66,67 zero.
__global__ __launch_bounds__(256) void k_fir(const float* __restrict__ x,
                                             ushort* __restrict__ xfn) {
  __shared__ float sxp[64 * 76];
  __shared__ float stp[68 * 68];
  const int plane = blockIdx.x;               // 0..4095
  const float* xp = x + (size_t)plane * 4096;
  ushort* op = xfn + (size_t)plane * PL;
  const int t = threadIdx.x;

  // zero halos
  {
    int r = t & 63, cs = t >> 6;
    int col = (cs < 2) ? (2 + cs) : (66 + cs);   // 2,3,68,69
    sxp[r * 76 + col] = 0.f;
  }
  for (int i = t; i < 272; i += 256) {           // 4 rows x 68
    int rr = i / 68, cc = i - rr * 68;
    int row = (rr < 2) ? rr : (64 + rr);         // 0,1,66,67
    stp[row * 68 + cc] = 0.f;
  }

  // stage plane: 1024 float4, b128 stores (16B aligned: col 4+4k, stride 76)
  const float4* x4 = (const float4*)xp;
#pragma unroll
  for (int i = 0; i < 4; ++i) {
    int f4 = t + 256 * i;
    int r = f4 >> 4, w4 = f4 & 15;
    *(float4*)&sxp[r * 76 + 4 + w4 * 4] = x4[f4];
  }
  __syncthreads();

  // horizontal: 64 rows x 17 groups of 4 outputs. out[j]=x[j-2]+3x[j-1]+3x[j]+x[j+1]
  for (int g = t; g < 1088; g += 256) {
    int i = g / 17, jg = g - i * 17;
    int j0 = jg << 2;
    const float* s = &sxp[i * 76 + j0];
    float4 a0 = *(const float4*)(s);        // w = j0-4 .. j0-1
    float4 a1 = *(const float4*)(s + 4);    // w = j0   .. j0+3
    float4 a2 = *(const float4*)(s + 8);    // w = j0+4 .. j0+7 (only .x used)
    float4 o;
    o.x = (a0.z + a1.y) + 3.f * (a0.w + a1.x);
    o.y = (a0.w + a1.z) + 3.f * (a1.x + a1.y);
    o.z = (a1.x + a1.w) + 3.f * (a1.y + a1.z);
    o.w = (a1.y + a2.x) + 3.f * (a1.z + a1.w);
    *(float4*)&stp[(i + 2) * 68 + j0] = o;  // junk cols >64 never used validly
  }
  __syncthreads();

  // vertical + store: 65 rows x 17 groups; out[i] = h[i-2]+3h[i-1]+3h[i]+h[i+1]
  for (int g = t; g < 1105; g += 256) {
    int i = g / 17, jg = g - i * 17;
    int j0 = jg << 2;
    const float* s = &stp[i * 68 + j0];
    float4 r0 = *(const float4*)(s);
    float4 r1 = *(const float4*)(s + 68);
    float4 r2 = *(const float4*)(s + 136);
    float4 r3 = *(const float4*)(s + 204);
    float4 o;
    o.x = (r0.x + r3.x) + 3.f * (r1.x + r2.x);
    o.y = (r0.y + r3.y) + 3.f * (r1.y + r2.y);
    o.z = (r0.z + r3.z) + 3.f * (r1.z + r2.z);
    o.w = (r0.w + r3.w) + 3.f * (r1.w + r2.w);
    ushort* q = op + i * 65 + j0;
    q[0] = f2bf(o.x * 0.015625f);
    if (j0 + 1 < 65) q[1] = f2bf(o.y * 0.015625f);
    if (j0 + 2 < 65) q[2] = f2bf(o.z * 0.015625f);
    if (j0 + 3 < 65) q[3] = f2bf(o.w * 0.015625f);
  }
}

// ---------------- Kernel 2: transpose NCHW -> NHWC (bf16) -----------------------
__global__ __launch_bounds__(256) void k_tr(const ushort* __restrict__ xfn,
                                            ushort* __restrict__ xft) {
  __shared__ ushort ld[64 * 68];
  const int hw0 = blockIdx.x * 64;
  const int c0 = blockIdx.y * 64;
  const int b = blockIdx.z;
  const int t = threadIdx.x;

#pragma unroll
  for (int i = 0; i < 4; ++i) {
    int idx = i * 256 + t;
    int cl = idx >> 4, hw4 = idx & 15;
    const ushort* sp = xfn + (size_t)(b * 256 + c0 + cl) * PL + hw0 + hw4 * 4;
    *(ushort4*)&ld[cl * 68 + hw4 * 4] = *(const ushort4*)sp;  // PL-padded: safe
  }
  __syncthreads();
#pragma unroll
  for (int i = 0; i < 4; ++i) {
    int idx = i * 256 + t;
    int hwl = idx >> 4, c4 = idx & 15;
    int hw = hw0 + hwl;
    if (hw < 4225) {
      ushort4 v;
      v.x = ld[(c4 * 4 + 0) * 68 + hwl];
      v.y = ld[(c4 * 4 + 1) * 68 + hwl];
      v.z = ld[(c4 * 4 + 2) * 68 + hwl];
      v.w = ld[(c4 * 4 + 3) * 68 + hwl];
      *(ushort4*)&xft[((size_t)(b * 4225 + hw) << 8) + c0 + c4 * 4] = v;
    }
  }
}

// ---------------- Kernel 3: w[oc][ic][3][3] f32 -> wb[oc][j*256+ic] bf16 --------
__global__ __launch_bounds__(256) void k_wcast2(const float* __restrict__ w,
                                                ushort* __restrict__ wb) {
  int iw = blockIdx.x * 256 + threadIdx.x;
  float v = w[iw];
  int j = iw % 9;
  int t2 = iw / 9;
  int ic = t2 & 255;
  int oc = t2 >> 8;
  wb[oc * KD + j * 256 + ic] = f2bf(v);
}

// ---------------- Kernel 4: implicit-conv GEMM, 2-phase double-buffer -----------
// C[oc=256][n=16384]; BM=128, BN=64, BK=64; 256 thr (4 waves 2m x 2n, 64x32 each)
__global__ __launch_bounds__(256) void k_gemm3(const ushort* __restrict__ Wb,
                                               const ushort* __restrict__ Xt,
                                               const float* __restrict__ bias,
                                               float* __restrict__ out) {
  __shared__ ushort lA[2][128 * 64];
  __shared__ ushort lB[2][64 * 64];
  const int bid = blockIdx.x;                      // 0..511
  const int work = (bid & 7) * 64 + (bid >> 3);    // XCD-chunked bijective
  const int ntile = work >> 1;
  const int mtile = work & 1;
  const int m0 = mtile * 128;
  const int n0 = ntile * 64;
  const int t = threadIdx.x;
  const int wid = t >> 6, lane = t & 63;
  const int wm = wid >> 1, wn = wid & 1;
  const int lrow = lane & 15, kgrp = lane >> 4;
  const int sw = lrow & 7;

  const ushort* aB[4];
#pragma unroll
  for (int i = 0; i < 4; ++i) {
    int idx = i * 256 + t;
    int row = idx >> 3;
    aB[i] = Wb + (size_t)(m0 + row) * KD + (((idx & 7) ^ (row & 7)) << 3);
  }
  const ushort* bB[2];
#pragma unroll
  for (int i = 0; i < 2; ++i) {
    int idx = i * 256 + t;
    int row = idx >> 3;
    int n = n0 + row;
    int b = n >> 10, oh = (n >> 5) & 31, ow = n & 31;
    bB[i] = Xt + ((size_t)((b * 65 + 2 * oh) * 65 + 2 * ow) << 8) +
            (((idx & 7) ^ (row & 7)) << 3);
  }

#define STAGE(buf, kt)                                                         \
  {                                                                            \
    const int j_ = (kt) >> 2;                                                  \
    const int dh_ = j_ / 3, dw_ = j_ - 3 * dh_;                                \
    const int boff_ = (dh_ * 65 + dw_) * 256 + (((kt) & 3) << 6);              \
    const int k0_ = (kt) << 6;                                                 \
    _Pragma("unroll") for (int i_ = 0; i_ < 4; ++i_)                           \
        GLDS16(aB[i_] + k0_, &lA[buf][(i_ * 256 + t) * 8]);                    \
    _Pragma("unroll") for (int i_ = 0; i_ < 2; ++i_)                           \
        GLDS16(bB[i_] + boff_, &lB[buf][(i_ * 256 + t) * 8]);                  \
  }

  f32x4 acc[4][2];
#pragma unroll
  for (int i = 0; i < 4; ++i)
#pragma unroll
    for (int j = 0; j < 2; ++j) acc[i][j] = (f32x4){0.f, 0.f, 0.f, 0.f};

  const int cA0 = ((kgrp ^ sw) << 3);
  const int cA1 = (((kgrp + 4) ^ sw) << 3);

  STAGE(0, 0);
  __syncthreads();                    // drains prologue stage (vmcnt 0)

  for (int kt = 0; kt < 36; ++kt) {
    const int cur = kt & 1;
    if (kt + 1 < 36) STAGE(cur ^ 1, kt + 1);   // issue next tile EARLY

    bf16x8 Af[4][2], Bf[2][2];
#pragma unroll
    for (int f = 0; f < 4; ++f) {
      int row = wm * 64 + f * 16 + lrow;
      Af[f][0] = *(const bf16x8*)&lA[cur][row * 64 + cA0];
      Af[f][1] = *(const bf16x8*)&lA[cur][row * 64 + cA1];
    }
#pragma unroll
    for (int f = 0; f < 2; ++f) {
      int row = wn * 32 + f * 16 + lrow;
      Bf[f][0] = *(const bf16x8*)&lB[cur][row * 64 + cA0];
      Bf[f][1] = *(const bf16x8*)&lB[cur][row * 64 + cA1];
    }
#pragma unroll
    for (int h = 0; h < 2; ++h)
#pragma unroll
      for (int fm = 0; fm < 4; ++fm)
#pragma unroll
        for (int fn = 0; fn < 2; ++fn)
          acc[fm][fn] = __builtin_amdgcn_mfma_f32_16x16x32_bf16(
              Af[fm][h], Bf[fn][h], acc[fm][fn], 0, 0, 0);

    __syncthreads();                  // vmcnt(0)+lgkmcnt(0)+barrier, once/iter
  }

  f32x4 bv[4];
#pragma unroll
  for (int fm = 0; fm < 4; ++fm)
    bv[fm] = *(const f32x4*)(bias + m0 + wm * 64 + fm * 16 + kgrp * 4);

#pragma unroll
  for (int fm = 0; fm < 4; ++fm) {
#pragma unroll
    for (int fn = 0; fn < 2; ++fn) {
      int nn = n0 + wn * 32 + fn * 16 + lrow;
      int oc = m0 + wm * 64 + fm * 16 + kgrp * 4;
      float* op = out + (size_t)(nn >> 10) * OUT_PER_B + (nn & 1023) +
                  (size_t)oc * 1024;
      op[0]    = acc[fm][fn][0] + bv[fm][0];
      op[1024] = acc[fm][fn][1] + bv[fm][1];
      op[2048] = acc[fm][fn][2] + bv[fm][2];
      op[3072] = acc[fm][fn][3] + bv[fm][3];
    }
  }
}

extern "C" void kernel_launch(void* const* d_in, const int* in_sizes, int n_in,
                              void* d_out, int out_size, void* d_ws, size_t ws_size,
                              hipStream_t stream) {
  const float* x    = (const float*)d_in[0];  // [16,256,64,64]
  const float* w    = (const float*)d_in[1];  // [256,256,3,3]
  const float* bias = (const float*)d_in[2];  // [256]
  float* out = (float*)d_out;                 // [16,256,32,32]

  char* ws = (char*)d_ws;
  ushort* xfn = (ushort*)ws;                        // 4096*4228*2 = 34,635,776 B
  ushort* xft = (ushort*)(ws + 34635776);           // 16*4225*256*2 = 34,611,200 B
  ushort* wb  = (ushort*)(ws + 34635776 + 34611200);// 1,179,648 B

  k_fir<<<4096, 256, 0, stream>>>(x, xfn);
  k_tr<<<dim3(67, 4, 16), 256, 0, stream>>>(xfn, xft);
  k_wcast2<<<2304, 256, 0, stream>>>(w, wb);
  k_gemm3<<<512, 256, 0, stream>>>(wb, xft, bias, out);
}

// Round 6
// 73.893 us; speedup vs baseline: 1.1816x; 1.1816x over previous
//
#include <hip/hip_runtime.h>
#include <hip/hip_bf16.h>

typedef __attribute__((ext_vector_type(8))) short bf16x8;
typedef __attribute__((ext_vector_type(4))) float f32x4;
typedef __attribute__((ext_vector_type(8))) unsigned short u16x8;

#define KD 2304
#define PL 4232                      // padded plane stride (elems), multiple of 8
#define OUT_PER_B (256 * 1024)

static __device__ __forceinline__ ushort f2bf(float f) {
  union { float f; unsigned int i; } v; v.f = f;
  unsigned int x = v.i;
  x += 0x7fffu + ((x >> 16) & 1u);   // round-to-nearest-even
  return (ushort)(x >> 16);
}

#define GLDS16(gp, lp)                                                         \
  __builtin_amdgcn_global_load_lds(                                            \
      (const __attribute__((address_space(1))) void*)(gp),                     \
      (__attribute__((address_space(3))) void*)(lp), 16, 0, 0)

// ---------------- Kernel 1: separable 4x4 FIR, pad 2, per (b,c) plane -----------
// f32 [64][64] -> bf16 [65][65] flat (plane stride PL). All LDS traffic b128.
__global__ __launch_bounds__(256) void k_fir(const float* __restrict__ x,
                                             ushort* __restrict__ xfn) {
  __shared__ float sxp[64 * 76];   // row r at cols 4..67; cols 2,3,68,69 zero halo
  __shared__ float stp[68 * 68];   // h-row i' at row i'+2; rows 0,1,66,67 zero
  const int plane = blockIdx.x;               // 0..4095
  const float* xp = x + (size_t)plane * 4096;
  ushort* op = xfn + (size_t)plane * PL;
  const int t = threadIdx.x;

  {
    int r = t & 63, cs = t >> 6;
    int col = (cs < 2) ? (2 + cs) : (66 + cs);   // 2,3,68,69
    sxp[r * 76 + col] = 0.f;
  }
  for (int i = t; i < 272; i += 256) {           // 4 rows x 68
    int rr = i / 68, cc = i - rr * 68;
    int row = (rr < 2) ? rr : (64 + rr);         // 0,1,66,67
    stp[row * 68 + cc] = 0.f;
  }

  const float4* x4 = (const float4*)xp;
#pragma unroll
  for (int i = 0; i < 4; ++i) {
    int f4 = t + 256 * i;
    int r = f4 >> 4, w4 = f4 & 15;
    *(float4*)&sxp[r * 76 + 4 + w4 * 4] = x4[f4];
  }
  __syncthreads();

  // horizontal: 64 rows x 17 groups of 4
  for (int g = t; g < 1088; g += 256) {
    int i = g / 17, jg = g - i * 17;
    int j0 = jg << 2;
    const float* s = &sxp[i * 76 + j0];
    float4 a0 = *(const float4*)(s);
    float4 a1 = *(const float4*)(s + 4);
    float4 a2 = *(const float4*)(s + 8);
    float4 o;
    o.x = (a0.z + a1.y) + 3.f * (a0.w + a1.x);
    o.y = (a0.w + a1.z) + 3.f * (a1.x + a1.y);
    o.z = (a1.x + a1.w) + 3.f * (a1.y + a1.z);
    o.w = (a1.y + a2.x) + 3.f * (a1.z + a1.w);
    *(float4*)&stp[(i + 2) * 68 + j0] = o;
  }
  __syncthreads();

  // vertical + store: 65 rows x 17 groups
  for (int g = t; g < 1105; g += 256) {
    int i = g / 17, jg = g - i * 17;
    int j0 = jg << 2;
    const float* s = &stp[i * 68 + j0];
    float4 r0 = *(const float4*)(s);
    float4 r1 = *(const float4*)(s + 68);
    float4 r2 = *(const float4*)(s + 136);
    float4 r3 = *(const float4*)(s + 204);
    float4 o;
    o.x = (r0.x + r3.x) + 3.f * (r1.x + r2.x);
    o.y = (r0.y + r3.y) + 3.f * (r1.y + r2.y);
    o.z = (r0.z + r3.z) + 3.f * (r1.z + r2.z);
    o.w = (r0.w + r3.w) + 3.f * (r1.w + r2.w);
    ushort* q = op + i * 65 + j0;
    q[0] = f2bf(o.x * 0.015625f);
    if (j0 + 1 < 65) q[1] = f2bf(o.y * 0.015625f);
    if (j0 + 2 < 65) q[2] = f2bf(o.z * 0.015625f);
    if (j0 + 3 < 65) q[3] = f2bf(o.w * 0.015625f);
  }
}

// ---------------- Kernel 2: transpose NCHW -> NHWC (bf16), 16B both sides -------
// tile [64 c][128 hw]; transpose on ds_write; LDS [hw][col] stride 66,
// col-group XOR swizzle: col = c ^ ((hw&7)<<3). grid (34, 4, 16).
__global__ __launch_bounds__(256) void k_tr(const ushort* __restrict__ xfn,
                                            ushort* __restrict__ xft) {
  __shared__ ushort ld[128 * 66];
  const int hw0 = blockIdx.x * 128;
  const int c0 = blockIdx.y * 64;
  const int b = blockIdx.z;
  const int t = threadIdx.x;

#pragma unroll
  for (int it = 0; it < 4; ++it) {
    int idx = it * 256 + t;                 // 0..1023
    int c = idx >> 4, q = idx & 15;         // c 0..63, q = hw chunk
    u16x8 v = {};
    if (hw0 + q * 8 < 4225)                 // stays inside the PL=4232 row
      v = *(const u16x8*)(xfn + (size_t)(b * 256 + c0 + c) * PL + hw0 + q * 8);
#pragma unroll
    for (int k = 0; k < 8; ++k)
      ld[(q * 8 + k) * 66 + (c ^ (k << 3))] = v[k];
  }
  __syncthreads();
#pragma unroll
  for (int it = 0; it < 4; ++it) {
    int idx = it * 256 + t;
    int hwl = idx >> 3, a = idx & 7;        // hwl 0..127, a = c-group
    int k7 = hwl & 7;
    int hw = hw0 + hwl;
    if (hw < 4225) {
      u16x8 v = *(const u16x8*)&ld[hwl * 66 + ((a ^ k7) << 3)];  // 4x b32, free
      *(u16x8*)&xft[((size_t)(b * 4225 + hw) << 8) + c0 + (a << 3)] = v;
    }
  }
}

// ---------------- Kernel 3: w[oc][ic][3][3] f32 -> wb[oc][j*256+ic] bf16 --------
__global__ __launch_bounds__(256) void k_wcast2(const float* __restrict__ w,
                                                ushort* __restrict__ wb) {
  int iw = blockIdx.x * 256 + threadIdx.x;
  float v = w[iw];
  int j = iw % 9;
  int t2 = iw / 9;
  int ic = t2 & 255;
  int oc = t2 >> 8;
  wb[oc * KD + j * 256 + ic] = f2bf(v);
}

// ---------------- Kernel 4: implicit-conv GEMM, m97 structure (PROVEN) ----------
// C[oc=256][n=16384]; BM=128, BN=64, BK=64; 256 thr (4 waves 2m x 2n, 64x32 each)
__global__ __launch_bounds__(256) void k_gemm3(const ushort* __restrict__ Wb,
                                               const ushort* __restrict__ Xt,
                                               const float* __restrict__ bias,
                                               float* __restrict__ out) {
  __shared__ ushort lA[128 * 64];
  __shared__ ushort lB[64 * 64];
  const int bid = blockIdx.x;                      // 0..511
  const int work = (bid & 7) * 64 + (bid >> 3);    // XCD-chunked bijective
  const int ntile = work >> 1;
  const int mtile = work & 1;
  const int m0 = mtile * 128;
  const int n0 = ntile * 64;
  const int t = threadIdx.x;
  const int wid = t >> 6, lane = t & 63;
  const int wm = wid >> 1, wn = wid & 1;
  const int lrow = lane & 15, kgrp = lane >> 4;
  const int sw = lrow & 7;

  const ushort* aB[4];
#pragma unroll
  for (int i = 0; i < 4; ++i) {
    int idx = i * 256 + t;
    int row = idx >> 3;
    aB[i] = Wb + (size_t)(m0 + row) * KD + (((idx & 7) ^ (row & 7)) << 3);
  }
  const ushort* bB[2];
#pragma unroll
  for (int i = 0; i < 2; ++i) {
    int idx = i * 256 + t;
    int row = idx >> 3;
    int n = n0 + row;
    int b = n >> 10, oh = (n >> 5) & 31, ow = n & 31;
    bB[i] = Xt + ((size_t)((b * 65 + 2 * oh) * 65 + 2 * ow) << 8) +
            (((idx & 7) ^ (row & 7)) << 3);
  }

  f32x4 acc[4][2];
#pragma unroll
  for (int i = 0; i < 4; ++i)
#pragma unroll
    for (int j = 0; j < 2; ++j) acc[i][j] = (f32x4){0.f, 0.f, 0.f, 0.f};

  const int cA0 = ((kgrp ^ sw) << 3);
  const int cA1 = (((kgrp + 4) ^ sw) << 3);

  for (int kt = 0; kt < 36; ++kt) {
    const int j = kt >> 2;
    const int dh = j / 3, dw = j - 3 * dh;
    const int boff = (dh * 65 + dw) * 256 + ((kt & 3) << 6);
    const int k0 = kt << 6;
    __syncthreads();
#pragma unroll
    for (int i = 0; i < 4; ++i)
      GLDS16(aB[i] + k0, &lA[(i * 256 + t) * 8]);
#pragma unroll
    for (int i = 0; i < 2; ++i)
      GLDS16(bB[i] + boff, &lB[(i * 256 + t) * 8]);
    __syncthreads();

    bf16x8 Af[4][2], Bf[2][2];
#pragma unroll
    for (int f = 0; f < 4; ++f) {
      int row = wm * 64 + f * 16 + lrow;
      Af[f][0] = *(const bf16x8*)&lA[row * 64 + cA0];
      Af[f][1] = *(const bf16x8*)&lA[row * 64 + cA1];
    }
#pragma unroll
    for (int f = 0; f < 2; ++f) {
      int row = wn * 32 + f * 16 + lrow;
      Bf[f][0] = *(const bf16x8*)&lB[row * 64 + cA0];
      Bf[f][1] = *(const bf16x8*)&lB[row * 64 + cA1];
    }
#pragma unroll
    for (int h = 0; h < 2; ++h)
#pragma unroll
      for (int fm = 0; fm < 4; ++fm)
#pragma unroll
        for (int fn = 0; fn < 2; ++fn)
          acc[fm][fn] = __builtin_amdgcn_mfma_f32_16x16x32_bf16(
              Af[fm][h], Bf[fn][h], acc[fm][fn], 0, 0, 0);
  }

  f32x4 bv[4];
#pragma unroll
  for (int fm = 0; fm < 4; ++fm)
    bv[fm] = *(const f32x4*)(bias + m0 + wm * 64 + fm * 16 + kgrp * 4);

#pragma unroll
  for (int fm = 0; fm < 4; ++fm) {
#pragma unroll
    for (int fn = 0; fn < 2; ++fn) {
      int nn = n0 + wn * 32 + fn * 16 + lrow;
      int oc = m0 + wm * 64 + fm * 16 + kgrp * 4;
      float* op = out + (size_t)(nn >> 10) * OUT_PER_B + (nn & 1023) +
                  (size_t)oc * 1024;
      op[0]    = acc[fm][fn][0] + bv[fm][0];
      op[1024] = acc[fm][fn][1] + bv[fm][1];
      op[2048] = acc[fm][fn][2] + bv[fm][2];
      op[3072] = acc[fm][fn][3] + bv[fm][3];
    }
  }
}

extern "C" void kernel_launch(void* const* d_in, const int* in_sizes, int n_in,
                              void* d_out, int out_size, void* d_ws, size_t ws_size,
                              hipStream_t stream) {
  const float* x    = (const float*)d_in[0];  // [16,256,64,64]
  const float* w    = (const float*)d_in[1];  // [256,256,3,3]
  const float* bias = (const float*)d_in[2];  // [256]
  float* out = (float*)d_out;                 // [16,256,32,32]

  char* ws = (char*)d_ws;
  ushort* xfn = (ushort*)ws;                        // 4096*4232*2 = 34,668,544 B
  ushort* xft = (ushort*)(ws + 34668544);           // 16*4225*256*2 = 34,611,200 B
  ushort* wb  = (ushort*)(ws + 34668544 + 34611200);// 1,179,648 B

  k_fir<<<4096, 256, 0, stream>>>(x, xfn);
  k_tr<<<dim3(34, 4, 16), 256, 0, stream>>>(xfn, xft);
  k_wcast2<<<2304, 256, 0, stream>>>(w, wb);
  k_gemm3<<<512, 256, 0, stream>>>(wb, xft, bias, out);
}

// Round 7
// 69.497 us; speedup vs baseline: 1.2563x; 1.0633x over previous
//
#include <hip/hip_runtime.h>
#include <hip/hip_bf16.h>

typedef __attribute__((ext_vector_type(8))) short bf16x8;
typedef __attribute__((ext_vector_type(4))) float f32x4;
typedef __attribute__((ext_vector_type(8))) unsigned short u16x8;

#define KD 2304
#define PL 4232                      // padded plane stride (elems), multiple of 8
#define OUT_PER_B (256 * 1024)

static __device__ __forceinline__ ushort f2bf(float f) {
  union { float f; unsigned int i; } v; v.f = f;
  unsigned int x = v.i;
  x += 0x7fffu + ((x >> 16) & 1u);   // round-to-nearest-even
  return (ushort)(x >> 16);
}

#define GLDS16(gp, lp)                                                         \
  __builtin_amdgcn_global_load_lds(                                            \
      (const __attribute__((address_space(1))) void*)(gp),                     \
      (__attribute__((address_space(3))) void*)(lp), 16, 0, 0)

// swizzle: 16-B chunk group g (0..15) of row r -> XOR low 3 bits with r&7
#define SWZ(g, r) (((g) & 8) | (((g) ^ (r)) & 7))

// ---------------- Kernel 1: separable 4x4 FIR + weight cast ---------------------
// f32 [64][64] -> bf16 [65][65] flat (plane stride PL). All LDS traffic b128.
// First 2304 blocks also convert 256 weight elems each (w -> wb[oc][j*256+ic]).
__global__ __launch_bounds__(256) void k_fir(const float* __restrict__ x,
                                             ushort* __restrict__ xfn,
                                             const float* __restrict__ w,
                                             ushort* __restrict__ wb) {
  __shared__ float sxp[64 * 76];   // row r at cols 4..67; cols 2,3,68,69 zero halo
  __shared__ float stp[68 * 68];   // h-row i' at row i'+2; rows 0,1,66,67 zero
  const int plane = blockIdx.x;               // 0..4095
  const float* xp = x + (size_t)plane * 4096;
  ushort* op = xfn + (size_t)plane * PL;
  const int t = threadIdx.x;

  // fused weight cast (independent global->global, no LDS, no barrier needed)
  if (plane < 2304) {
    int iw = plane * 256 + t;
    float v = w[iw];
    int j = iw % 9;
    int t2 = iw / 9;
    int ic = t2 & 255;
    int oc = t2 >> 8;
    wb[oc * KD + j * 256 + ic] = f2bf(v);
  }

  {
    int r = t & 63, cs = t >> 6;
    int col = (cs < 2) ? (2 + cs) : (66 + cs);   // 2,3,68,69
    sxp[r * 76 + col] = 0.f;
  }
  for (int i = t; i < 272; i += 256) {           // 4 rows x 68
    int rr = i / 68, cc = i - rr * 68;
    int row = (rr < 2) ? rr : (64 + rr);         // 0,1,66,67
    stp[row * 68 + cc] = 0.f;
  }

  const float4* x4 = (const float4*)xp;
#pragma unroll
  for (int i = 0; i < 4; ++i) {
    int f4 = t + 256 * i;
    int r = f4 >> 4, w4 = f4 & 15;
    *(float4*)&sxp[r * 76 + 4 + w4 * 4] = x4[f4];
  }
  __syncthreads();

  // horizontal: 64 rows x 17 groups of 4
  for (int g = t; g < 1088; g += 256) {
    int i = g / 17, jg = g - i * 17;
    int j0 = jg << 2;
    const float* s = &sxp[i * 76 + j0];
    float4 a0 = *(const float4*)(s);
    float4 a1 = *(const float4*)(s + 4);
    float4 a2 = *(const float4*)(s + 8);
    float4 o;
    o.x = (a0.z + a1.y) + 3.f * (a0.w + a1.x);
    o.y = (a0.w + a1.z) + 3.f * (a1.x + a1.y);
    o.z = (a1.x + a1.w) + 3.f * (a1.y + a1.z);
    o.w = (a1.y + a2.x) + 3.f * (a1.z + a1.w);
    *(float4*)&stp[(i + 2) * 68 + j0] = o;
  }
  __syncthreads();

  // vertical + store: 65 rows x 17 groups
  for (int g = t; g < 1105; g += 256) {
    int i = g / 17, jg = g - i * 17;
    int j0 = jg << 2;
    const float* s = &stp[i * 68 + j0];
    float4 r0 = *(const float4*)(s);
    float4 r1 = *(const float4*)(s + 68);
    float4 r2 = *(const float4*)(s + 136);
    float4 r3 = *(const float4*)(s + 204);
    float4 o;
    o.x = (r0.x + r3.x) + 3.f * (r1.x + r2.x);
    o.y = (r0.y + r3.y) + 3.f * (r1.y + r2.y);
    o.z = (r0.z + r3.z) + 3.f * (r1.z + r2.z);
    o.w = (r0.w + r3.w) + 3.f * (r1.w + r2.w);
    ushort* q = op + i * 65 + j0;
    q[0] = f2bf(o.x * 0.015625f);
    if (j0 + 1 < 65) q[1] = f2bf(o.y * 0.015625f);
    if (j0 + 2 < 65) q[2] = f2bf(o.z * 0.015625f);
    if (j0 + 3 < 65) q[3] = f2bf(o.w * 0.015625f);
  }
}

// ---------------- Kernel 2: transpose NCHW -> NHWC (bf16), 16B both sides -------
__global__ __launch_bounds__(256) void k_tr(const ushort* __restrict__ xfn,
                                            ushort* __restrict__ xft) {
  __shared__ ushort ld[128 * 66];
  const int hw0 = blockIdx.x * 128;
  const int c0 = blockIdx.y * 64;
  const int b = blockIdx.z;
  const int t = threadIdx.x;

#pragma unroll
  for (int it = 0; it < 4; ++it) {
    int idx = it * 256 + t;                 // 0..1023
    int c = idx >> 4, q = idx & 15;         // c 0..63, q = hw chunk
    u16x8 v = {};
    if (hw0 + q * 8 < 4225)                 // stays inside the PL=4232 row
      v = *(const u16x8*)(xfn + (size_t)(b * 256 + c0 + c) * PL + hw0 + q * 8);
#pragma unroll
    for (int k = 0; k < 8; ++k)
      ld[(q * 8 + k) * 66 + (c ^ (k << 3))] = v[k];
  }
  __syncthreads();
#pragma unroll
  for (int it = 0; it < 4; ++it) {
    int idx = it * 256 + t;
    int hwl = idx >> 3, a = idx & 7;        // hwl 0..127, a = c-group
    int k7 = hwl & 7;
    int hw = hw0 + hwl;
    if (hw < 4225) {
      u16x8 v = *(const u16x8*)&ld[hwl * 66 + ((a ^ k7) << 3)];  // 4x b32, free
      *(u16x8*)&xft[((size_t)(b * 4225 + hw) << 8) + c0 + (a << 3)] = v;
    }
  }
}

// ---------------- Kernel 3: implicit-conv GEMM, m97 structure, BK=128 -----------
// C[oc=256][n=16384]; BM=128, BN=64, BK=128; 256 thr (4 waves 2m x 2n, 64x32 each)
// 18 K-iterations (9 taps x 2 ic-halves), 2 barriers/iter.
__global__ __launch_bounds__(256) void k_gemm3(const ushort* __restrict__ Wb,
                                               const ushort* __restrict__ Xt,
                                               const float* __restrict__ bias,
                                               float* __restrict__ out) {
  __shared__ ushort lA[128 * 128];                 // 32 KB
  __shared__ ushort lB[64 * 128];                  // 16 KB
  const int bid = blockIdx.x;                      // 0..511
  const int work = (bid & 7) * 64 + (bid >> 3);    // XCD-chunked bijective
  const int ntile = work >> 1;
  const int mtile = work & 1;
  const int m0 = mtile * 128;
  const int n0 = ntile * 64;
  const int t = threadIdx.x;
  const int wid = t >> 6, lane = t & 63;
  const int wm = wid >> 1, wn = wid & 1;
  const int lrow = lane & 15, kgrp = lane >> 4;

  // staging source pointers (linear LDS dest idx*8; source col pre-swizzled)
  const ushort* aB[8];
#pragma unroll
  for (int i = 0; i < 8; ++i) {
    int idx = i * 256 + t;
    int row = idx >> 4, gL = idx & 15;
    aB[i] = Wb + (size_t)(m0 + row) * KD + SWZ(gL, row) * 8;
  }
  const ushort* bB[4];
#pragma unroll
  for (int i = 0; i < 4; ++i) {
    int idx = i * 256 + t;
    int row = idx >> 4, gL = idx & 15;
    int n = n0 + row;
    int b = n >> 10, oh = (n >> 5) & 31, ow = n & 31;
    bB[i] = Xt + ((size_t)((b * 65 + 2 * oh) * 65 + 2 * ow) << 8) +
            SWZ(gL, row) * 8;
  }

  f32x4 acc[4][2];
#pragma unroll
  for (int i = 0; i < 4; ++i)
#pragma unroll
    for (int j = 0; j < 2; ++j) acc[i][j] = (f32x4){0.f, 0.f, 0.f, 0.f};

  for (int kt = 0; kt < 18; ++kt) {
    const int j = kt >> 1;
    const int dh = j / 3, dw = j - 3 * dh;
    const int boff = (dh * 65 + dw) * 256 + ((kt & 1) << 7);
    const int k0 = kt << 7;
    __syncthreads();
#pragma unroll
    for (int i = 0; i < 8; ++i)
      GLDS16(aB[i] + k0, &lA[(i * 256 + t) * 8]);
#pragma unroll
    for (int i = 0; i < 4; ++i)
      GLDS16(bB[i] + boff, &lB[(i * 256 + t) * 8]);
    __syncthreads();

#pragma unroll
    for (int s = 0; s < 4; ++s) {
      bf16x8 Af[4], Bf[2];
#pragma unroll
      for (int f = 0; f < 4; ++f) {
        int row = wm * 64 + f * 16 + lrow;
        Af[f] = *(const bf16x8*)&lA[row * 128 + SWZ(s * 4 + kgrp, row) * 8];
      }
#pragma unroll
      for (int f = 0; f < 2; ++f) {
        int row = wn * 32 + f * 16 + lrow;
        Bf[f] = *(const bf16x8*)&lB[row * 128 + SWZ(s * 4 + kgrp, row) * 8];
      }
#pragma unroll
      for (int fm = 0; fm < 4; ++fm)
#pragma unroll
        for (int fn = 0; fn < 2; ++fn)
          acc[fm][fn] = __builtin_amdgcn_mfma_f32_16x16x32_bf16(
              Af[fm], Bf[fn], acc[fm][fn], 0, 0, 0);
    }
  }

  f32x4 bv[4];
#pragma unroll
  for (int fm = 0; fm < 4; ++fm)
    bv[fm] = *(const f32x4*)(bias + m0 + wm * 64 + fm * 16 + kgrp * 4);

#pragma unroll
  for (int fm = 0; fm < 4; ++fm) {
#pragma unroll
    for (int fn = 0; fn < 2; ++fn) {
      int nn = n0 + wn * 32 + fn * 16 + lrow;
      int oc = m0 + wm * 64 + fm * 16 + kgrp * 4;
      float* op = out + (size_t)(nn >> 10) * OUT_PER_B + (nn & 1023) +
                  (size_t)oc * 1024;
      op[0]    = acc[fm][fn][0] + bv[fm][0];
      op[1024] = acc[fm][fn][1] + bv[fm][1];
      op[2048] = acc[fm][fn][2] + bv[fm][2];
      op[3072] = acc[fm][fn][3] + bv[fm][3];
    }
  }
}

extern "C" void kernel_launch(void* const* d_in, const int* in_sizes, int n_in,
                              void* d_out, int out_size, void* d_ws, size_t ws_size,
                              hipStream_t stream) {
  const float* x    = (const float*)d_in[0];  // [16,256,64,64]
  const float* w    = (const float*)d_in[1];  // [256,256,3,3]
  const float* bias = (const float*)d_in[2];  // [256]
  float* out = (float*)d_out;                 // [16,256,32,32]

  char* ws = (char*)d_ws;
  ushort* xfn = (ushort*)ws;                        // 4096*4232*2 = 34,668,544 B
  ushort* xft = (ushort*)(ws + 34668544);           // 16*4225*256*2 = 34,611,200 B
  ushort* wb  = (ushort*)(ws + 34668544 + 34611200);// 1,179,648 B

  k_fir<<<4096, 256, 0, stream>>>(x, xfn, w, wb);
  k_tr<<<dim3(34, 4, 16), 256, 0, stream>>>(xfn, xft);
  k_gemm3<<<512, 256, 0, stream>>>(wb, xft, bias, out);
}